// Round 1
// baseline (142.119 us; speedup 1.0000x reference)
//
#include <hip/hip_runtime.h>
#include <cstdint>

#define NB 256       // batches
#define NQ 1000
#define NC 80
#define QC 80000     // NQ*NC
#define TOPK 300
#define CAND_CAP 6144
#define SORT_CAP 1024
#define NTHREADS 1024
#define PREFILTER 2.0f

// monotonic order-preserving transform f32 bits -> u32 (larger key = larger float)
__device__ __forceinline__ uint32_t fkey(uint32_t u) {
  return (u & 0x80000000u) ? ~u : (u | 0x80000000u);
}

__global__ __launch_bounds__(NTHREADS) void rtdetr_post_kernel(
    const float* __restrict__ logits,
    const float* __restrict__ boxes,
    const float* __restrict__ sizes,
    float* __restrict__ out) {
  __shared__ uint64_t cand[CAND_CAP];
  __shared__ uint64_t sortBuf[SORT_CAP];
  __shared__ uint32_t hist[256];
  __shared__ uint32_t scanb[256];
  __shared__ int sCount;
  __shared__ int sNsort;
  __shared__ int sKRem;
  __shared__ uint32_t sDigit;

  const int b   = blockIdx.x;
  const int tid = threadIdx.x;
  const int lane = tid & 63;
  const uint64_t laneLt = (lane == 0) ? 0ull : (~0ull >> (64 - lane));

  if (tid == 0) { sCount = 0; sNsort = 0; }
  __syncthreads();

  // ---------- Phase 1: stream logits, prefilter, wave-aggregated push ----------
  const float4* lg4 = (const float4*)(logits + (size_t)b * QC);
  // 20000 float4s; pad to 20480 so every thread does 20 uniform iterations
  for (int i = tid; i < 20480; i += NTHREADS) {
    float4 v = make_float4(-100.f, -100.f, -100.f, -100.f);
    if (i < QC / 4) v = lg4[i];
    float comp[4] = {v.x, v.y, v.z, v.w};
#pragma unroll
    for (int c = 0; c < 4; ++c) {
      float x = comp[c];
      bool pred = (x > PREFILTER);
      uint64_t item = 0;
      if (pred) {
        uint32_t k = fkey(__float_as_uint(x));
        uint32_t idx = (uint32_t)(i * 4 + c);
        item = ((uint64_t)k << 32) | (uint32_t)(~idx);
      }
      unsigned long long m = __ballot(pred);
      if (m) {
        int leader = __builtin_ctzll(m);
        int rank = __popcll(m & laneLt);
        int base = 0;
        if (lane == leader) base = atomicAdd(&sCount, __popcll(m));
        base = __shfl(base, leader, 64);
        if (pred) {
          int pos = base + rank;
          if (pos < CAND_CAP) cand[pos] = item;
        }
      }
    }
  }
  __syncthreads();
  int count = sCount;
  if (count > CAND_CAP) count = CAND_CAP;

  // ---------- Phase 2: 4-round radix select on key (top 32 bits) ----------
  uint32_t prefix = 0, mask = 0;
  int kRem = TOPK;
  for (int r = 3; r >= 0; --r) {
    const int sh = r * 8;
    if (tid < 256) hist[tid] = 0;
    __syncthreads();
    for (int i = tid; i < count; i += NTHREADS) {
      uint32_t key = (uint32_t)(cand[i] >> 32);
      if ((key & mask) == prefix) atomicAdd(&hist[(key >> sh) & 255], 1u);
    }
    __syncthreads();
    // inclusive suffix scan: scanb[d] = sum_{d' >= d} hist[d']
    if (tid < 256) scanb[tid] = hist[tid];
    __syncthreads();
    for (int s = 1; s < 256; s <<= 1) {
      uint32_t add = 0;
      if (tid < 256 && tid + s < 256) add = scanb[tid + s];
      __syncthreads();
      if (tid < 256) scanb[tid] += add;
      __syncthreads();
    }
    // pick largest digit d with suffix-count >= kRem
    if (tid < 256) {
      bool p  = (scanb[tid] >= (uint32_t)kRem);
      bool pn = (tid < 255) && (scanb[tid + 1] >= (uint32_t)kRem);
      if (p && !pn) {
        sDigit = (uint32_t)tid;
        sKRem  = kRem - (int)(scanb[tid] - hist[tid]);
      }
    }
    __syncthreads();
    prefix |= sDigit << sh;
    mask   |= 0xFFu << sh;
    kRem    = sKRem;
    __syncthreads();
  }
  const uint32_t T = prefix;  // exact key of the 300th-largest value

  // ---------- Phase 3: compact key >= T, bitonic sort descending ----------
  const int countPad = (count + NTHREADS - 1) & ~(NTHREADS - 1);
  for (int i = tid; i < countPad; i += NTHREADS) {
    bool pred = false;
    uint64_t item = 0;
    if (i < count) {
      item = cand[i];
      pred = ((uint32_t)(item >> 32)) >= T;
    }
    unsigned long long m = __ballot(pred);
    if (m) {
      int leader = __builtin_ctzll(m);
      int rank = __popcll(m & laneLt);
      int base = 0;
      if (lane == leader) base = atomicAdd(&sNsort, __popcll(m));
      base = __shfl(base, leader, 64);
      if (pred) {
        int pos = base + rank;
        if (pos < SORT_CAP) sortBuf[pos] = item;
      }
    }
  }
  __syncthreads();
  int nsort = sNsort;
  if (nsort > SORT_CAP) nsort = SORT_CAP;
  for (int i = tid; i < SORT_CAP; i += NTHREADS)
    if (i >= nsort) sortBuf[i] = 0;  // pad sinks to the end (all real keys > 0xC0000000)
  __syncthreads();

  // bitonic sort, descending by composite (key desc, idx asc via ~idx)
  for (int k = 2; k <= SORT_CAP; k <<= 1) {
    for (int j = k >> 1; j > 0; j >>= 1) {
      const int i = tid;
      const int l = i ^ j;
      if (l > i) {
        uint64_t a = sortBuf[i];
        uint64_t c = sortBuf[l];
        const bool dirDesc = ((i & k) == 0);
        const bool doSwap = dirDesc ? (a < c) : (a > c);
        if (doSwap) { sortBuf[i] = c; sortBuf[l] = a; }
      }
      __syncthreads();
    }
  }

  // ---------- Phase 4: decode + write outputs ----------
  if (tid < TOPK) {
    const uint64_t item = sortBuf[tid];
    const uint32_t key = (uint32_t)(item >> 32);
    const uint32_t idx = ~((uint32_t)item);
    const int q  = (int)(idx / NC);
    const int cl = (int)(idx - (uint32_t)q * NC);
    // invert key -> float bits
    const uint32_t u = (key & 0x80000000u) ? (key ^ 0x80000000u) : ~key;
    const float x = __uint_as_float(u);
    const float score = 1.0f / (1.0f + expf(-x));

    const float4 bx = ((const float4*)boxes)[b * NQ + q];
    const float W = sizes[2 * b];
    const float H = sizes[2 * b + 1];
    const float hw = 0.5f * bx.z;
    const float hh = 0.5f * bx.w;

    // labels [NB, TOPK]
    out[b * TOPK + tid] = (float)cl;
    // boxes  [NB, TOPK, 4] after labels
    float* ob = out + (size_t)NB * TOPK + ((size_t)b * TOPK + tid) * 4;
    ob[0] = (bx.x - hw) * W;
    ob[1] = (bx.y - hh) * H;
    ob[2] = (bx.x + hw) * W;
    ob[3] = (bx.y + hh) * H;
    // scores [NB, TOPK] after boxes
    out[(size_t)NB * TOPK * 5 + b * TOPK + tid] = score;
  }
}

extern "C" void kernel_launch(void* const* d_in, const int* in_sizes, int n_in,
                              void* d_out, int out_size, void* d_ws, size_t ws_size,
                              hipStream_t stream) {
  const float* logits = (const float*)d_in[0];
  const float* boxes  = (const float*)d_in[1];
  const float* sizes  = (const float*)d_in[2];
  float* out = (float*)d_out;
  (void)in_sizes; (void)n_in; (void)out_size; (void)d_ws; (void)ws_size;
  rtdetr_post_kernel<<<dim3(NB), dim3(NTHREADS), 0, stream>>>(logits, boxes, sizes, out);
}